// Round 9
// baseline (411.700 us; speedup 1.0000x reference)
//
#include <hip/hip_runtime.h>
#include <math.h>

// GCN: 7 graph-conv layers. N=65536 nodes, E=1048576 edges, feat 128->64(x6)->40.
// dst-CSR once per call (4-way spread histogram to cut atomic line contention);
// per layer {register-blocked GEMM -> bf16 support, flat-issue pull-aggregate}.

constexpr int NFEAT = 128, NHID = 64, NCLASS = 40;

typedef unsigned short ushort_t;
typedef int ivec4 __attribute__((ext_vector_type(4)));   // native vec for nt-store

__device__ inline float bf2f(ushort_t u) {
  union { unsigned int i; float f; } v; v.i = ((unsigned int)u) << 16; return v.f;
}
__device__ inline ushort_t f2bf(float f) {  // round-to-nearest-even
  union { float f; unsigned int i; } v; v.f = f;
  unsigned int lsb = (v.i >> 16) & 1u;
  v.i += 0x7fffu + lsb;
  return (ushort_t)(v.i >> 16);
}

// Histogram + per-edge rank. 4 sub-histograms (cnt4[s*N+d]) so same-sector
// atomic RMWs are spread 4x; edge j of each int4 group uses sub-array j.
// rank encodes (subrank<<2)|s.
__global__ void rank_k(const int* __restrict__ dst, int* __restrict__ cnt4,
                       int* __restrict__ rank, int E, int N) {
  int i = blockIdx.x * blockDim.x + threadIdx.x;
  int base = i * 4;
  if (base >= E) return;
  int4 d4 = *(const int4*)(dst + base);   // E % 4 == 0
  int r0 = atomicAdd(&cnt4[0 * N + d4.x], 1);
  int r1 = atomicAdd(&cnt4[1 * N + d4.y], 1);
  int r2 = atomicAdd(&cnt4[2 * N + d4.z], 1);
  int r3 = atomicAdd(&cnt4[3 * N + d4.w], 1);
  ivec4 rr = { (r0 << 2) | 0, (r1 << 2) | 1, (r2 << 2) | 2, (r3 << 2) | 3 };
  __builtin_nontemporal_store(rr, (ivec4*)(rank + base));
}

// Block scan of per-node totals; also emits per-node sub-bases sb4.
__global__ void scan1_k(const int* __restrict__ cnt4, int* __restrict__ off,
                        int* __restrict__ bsum, int4* __restrict__ sb4, int n) {
  __shared__ int tmp[256];
  int tid = threadIdx.x;
  int i = blockIdx.x * 256 + tid;
  int c0 = 0, c1 = 0, c2 = 0, c3 = 0;
  if (i < n) {
    c0 = cnt4[i]; c1 = cnt4[n + i]; c2 = cnt4[2 * n + i]; c3 = cnt4[3 * n + i];
  }
  int v = c0 + c1 + c2 + c3;
  tmp[tid] = v;
  __syncthreads();
  for (int d = 1; d < 256; d <<= 1) {
    int t = (tid >= d) ? tmp[tid - d] : 0;
    __syncthreads();
    tmp[tid] += t;
    __syncthreads();
  }
  if (i < n) {
    off[i] = tmp[tid] - v;  // exclusive (within block)
    sb4[i] = make_int4(0, c0, c0 + c1, c0 + c1 + c2);
  }
  if (tid == 255) bsum[blockIdx.x] = tmp[255];
}

__global__ void scan2_k(int* __restrict__ bsum, int nb) {
  __shared__ int tmp[256];
  int tid = threadIdx.x;
  int v = (tid < nb) ? bsum[tid] : 0;
  tmp[tid] = v;
  __syncthreads();
  for (int d = 1; d < 256; d <<= 1) {
    int t = (tid >= d) ? tmp[tid - d] : 0;
    __syncthreads();
    tmp[tid] += t;
    __syncthreads();
  }
  if (tid < nb) bsum[tid] = tmp[tid] - v;  // exclusive
}

__global__ void scan3_k(int* __restrict__ off, const int* __restrict__ bsum, int n, int E) {
  int i = blockIdx.x * blockDim.x + threadIdx.x;
  if (i < n) off[i] += bsum[i >> 8];
  if (i == 0) off[n] = E;
}

// Atomic-free scatter: pos = off[d] + sb4[d][s] + subrank, non-temporal store.
__global__ void fill_k(const int* __restrict__ src, const int* __restrict__ dst,
                       const float* __restrict__ w, const int* __restrict__ off,
                       const int* __restrict__ rank, const int* __restrict__ sb4,
                       int2* __restrict__ edata, int E) {
  int i = blockIdx.x * blockDim.x + threadIdx.x;
  if (i < E) {
    int d = dst[i];
    int rp = rank[i];
    int s = rp & 3, sr = rp >> 2;
    int pos = off[d] + sb4[d * 4 + s] + sr;
    int2 v = make_int2(src[i], __float_as_int(w[i]));
    __builtin_nontemporal_store(*(const long long*)&v, (long long*)&edata[pos]);
  }
}

// Register-blocked GEMM: 64x64 tile / 256-thread block, 4x4 per thread.
// Output written as bf16 (support tables).
template<int FI, int FO>
__global__ __launch_bounds__(256) void gemm_k(const float* __restrict__ h,
                                              const float* __restrict__ W,
                                              ushort_t* __restrict__ out, int n) {
  constexpr int HS = 68;            // h_lds row stride, pad 4
  __shared__ float hl[64 * HS];     // 17408 B
  __shared__ float wl[64 * 64];     // 16384 B
  int tid = threadIdx.x;
  int row0 = blockIdx.x * 64;
  int tx = tid & 15, ty = tid >> 4;

  float acc[4][4] = {};

  for (int kc = 0; kc < FI; kc += 64) {
    {
      const float* hb = h + (size_t)row0 * FI + kc;
      for (int i = tid; i < 64 * 16; i += 256) {
        int r = i >> 4, kk = (i & 15) << 2;
        float4 v = *(const float4*)(hb + (size_t)r * FI + kk);
        *(float4*)&hl[r * HS + kk] = v;
      }
    }
    if (FO == 64) {
      const float4* Wb = (const float4*)(W + (size_t)kc * 64);
      for (int i = tid; i < 64 * 16; i += 256) ((float4*)wl)[i] = Wb[i];
    } else {
      for (int i = tid; i < 64 * 64; i += 256) wl[i] = 0.0f;
      __syncthreads();
      for (int i = tid; i < 64 * FO; i += 256)
        wl[(i / FO) * 64 + (i % FO)] = W[(size_t)(kc + i / FO) * FO + (i % FO)];
    }
    __syncthreads();

    for (int k4 = 0; k4 < 64; k4 += 4) {
      float4 a[4];
#pragma unroll
      for (int r = 0; r < 4; ++r)
        a[r] = *(const float4*)&hl[(ty * 4 + r) * HS + k4];
#pragma unroll
      for (int j = 0; j < 4; ++j) {
        float4 bv = *(const float4*)&wl[(k4 + j) * 64 + tx * 4];
        const float* bp = (const float*)&bv;
#pragma unroll
        for (int r = 0; r < 4; ++r) {
          const float* ap = (const float*)&a[r];
#pragma unroll
          for (int c = 0; c < 4; ++c) acc[r][c] += ap[j] * bp[c];
        }
      }
    }
    __syncthreads();
  }

  if (FO == 64) {
#pragma unroll
    for (int r = 0; r < 4; ++r) {
      ushort_t pk[4];
#pragma unroll
      for (int c = 0; c < 4; ++c) pk[c] = f2bf(acc[r][c]);
      *(ushort4*)&out[(size_t)(row0 + ty * 4 + r) * 64 + tx * 4] =
          make_ushort4(pk[0], pk[1], pk[2], pk[3]);
    }
  } else {
#pragma unroll
    for (int r = 0; r < 4; ++r)
#pragma unroll
      for (int c = 0; c < 4; ++c) {
        int col = tx * 4 + c;
        if (col < FO) out[(size_t)(row0 + ty * 4 + r) * FO + col] = f2bf(acc[r][c]);
      }
  }
}

// Pull aggregation: one wave per node. Lanes 0-31 = even edges, 32-63 = odd;
// lane loads 2 bf16 feats per gather. Flat-issue body: all 16 src loads, then
// all 16 gathers, then all 16 weight loads are in flight before any use.
__global__ __launch_bounds__(256, 8) void agg_k(
    const ushort_t* __restrict__ support,
    const int2* __restrict__ edata,
    const int* __restrict__ off,
    const float* __restrict__ bias,
    const float* __restrict__ resid,
    float* __restrict__ out,
    int n, int do_relu) {
  int tid = blockIdx.x * blockDim.x + threadIdx.x;
  int wid = tid >> 6, lane = tid & 63;
  if (wid >= n) return;
  int half = lane >> 5;   // which edge of the pair
  int hl   = lane & 31;   // feature pair (feats 2hl, 2hl+1)
  int e0 = __builtin_amdgcn_readfirstlane(off[wid]);
  int e1 = __builtin_amdgcn_readfirstlane(off[wid + 1]);
  int deg = e1 - e0;

  const ushort_t* sp = support + hl * 2;      // per-lane feature base
  const int* epi = (const int*)(edata + e0);  // int view of this node's edges

  float ax[4] = {}, ay[4] = {};
  if (deg > 0) {
    // ---- flat 32-edge body (masked) ----
    int sx[16];
#pragma unroll
    for (int j = 0; j < 16; ++j) {
      int rel = 2 * j + half;
      sx[j] = epi[(rel < deg ? rel : 0) * 2];          // src index
    }
    unsigned int u[16];
#pragma unroll
    for (int j = 0; j < 16; ++j)
      u[j] = *(const unsigned int*)(sp + ((size_t)sx[j] << 6));
    float wv[16];
#pragma unroll
    for (int j = 0; j < 16; ++j) {
      int rel = 2 * j + half;
      wv[j] = (rel < deg) ? __int_as_float(epi[rel * 2 + 1]) : 0.0f;
    }
#pragma unroll
    for (int j = 0; j < 16; ++j) {
      ax[j & 3] += wv[j] * __int_as_float(u[j] << 16);
      ay[j & 3] += wv[j] * __int_as_float(u[j] & 0xffff0000u);
    }
    // ---- rare remainder (deg > 32): masked 16-edge chunks ----
    for (int it = 32; it < deg; it += 16) {
      int2 ed[8];
#pragma unroll
      for (int j = 0; j < 8; ++j) {
        int rel = it + 2 * j + half;
        ed[j] = *(const int2*)(epi + (rel < deg ? rel : 0) * 2);
      }
      unsigned int uu[8];
#pragma unroll
      for (int j = 0; j < 8; ++j)
        uu[j] = *(const unsigned int*)(sp + ((size_t)ed[j].x << 6));
#pragma unroll
      for (int j = 0; j < 8; ++j) {
        int rel = it + 2 * j + half;
        float w = (rel < deg) ? __int_as_float(ed[j].y) : 0.0f;
        ax[j & 3] += w * __int_as_float(uu[j] << 16);
        ay[j & 3] += w * __int_as_float(uu[j] & 0xffff0000u);
      }
    }
  }
  float sx2 = (ax[0] + ax[1]) + (ax[2] + ax[3]);
  float sy2 = (ay[0] + ay[1]) + (ay[2] + ay[3]);
  sx2 += __shfl_xor(sx2, 32, 64);
  sy2 += __shfl_xor(sy2, 32, 64);
  if (half == 0) {
    float2 bv = *(const float2*)&bias[hl * 2];
    float vx = sx2 + bv.x, vy = sy2 + bv.y;
    if (do_relu) { vx = fmaxf(vx, 0.0f); vy = fmaxf(vy, 0.0f); }
    if (resid) {
      float2 r = *(const float2*)&resid[(size_t)wid * 64 + hl * 2];
      vx += r.x; vy += r.y;
    }
    *(float2*)&out[(size_t)wid * 64 + hl * 2] = make_float2(vx, vy);
  }
}

// Final layer: FO=40, same flat-issue scheme (feat pairs 0..19 valid), then
// bias + log_softmax over 40 classes via 64-lane butterflies.
__global__ __launch_bounds__(256, 8) void agg_final_k(
    const ushort_t* __restrict__ support,
    const int2* __restrict__ edata,
    const int* __restrict__ off,
    const float* __restrict__ bias,
    float* __restrict__ out, int n) {
  int tid = blockIdx.x * blockDim.x + threadIdx.x;
  int wid = tid >> 6, lane = tid & 63;
  if (wid >= n) return;
  int half = lane >> 5;
  int hl   = lane & 31;
  int col  = (hl < 20 ? hl : 0) * 2;   // clamp to stay in-row
  int e0 = __builtin_amdgcn_readfirstlane(off[wid]);
  int e1 = __builtin_amdgcn_readfirstlane(off[wid + 1]);
  int deg = e1 - e0;

  const ushort_t* sp = support + col;
  const int* epi = (const int*)(edata + e0);

  float ax[4] = {}, ay[4] = {};
  if (deg > 0) {
    int sx[16];
#pragma unroll
    for (int j = 0; j < 16; ++j) {
      int rel = 2 * j + half;
      sx[j] = epi[(rel < deg ? rel : 0) * 2];
    }
    unsigned int u[16];
#pragma unroll
    for (int j = 0; j < 16; ++j)
      u[j] = *(const unsigned int*)(sp + (size_t)sx[j] * NCLASS);
    float wv[16];
#pragma unroll
    for (int j = 0; j < 16; ++j) {
      int rel = 2 * j + half;
      wv[j] = (rel < deg) ? __int_as_float(epi[rel * 2 + 1]) : 0.0f;
    }
#pragma unroll
    for (int j = 0; j < 16; ++j) {
      ax[j & 3] += wv[j] * __int_as_float(u[j] << 16);
      ay[j & 3] += wv[j] * __int_as_float(u[j] & 0xffff0000u);
    }
    for (int it = 32; it < deg; it += 16) {
      int2 ed[8];
#pragma unroll
      for (int j = 0; j < 8; ++j) {
        int rel = it + 2 * j + half;
        ed[j] = *(const int2*)(epi + (rel < deg ? rel : 0) * 2);
      }
      unsigned int uu[8];
#pragma unroll
      for (int j = 0; j < 8; ++j)
        uu[j] = *(const unsigned int*)(sp + (size_t)ed[j].x * NCLASS);
#pragma unroll
      for (int j = 0; j < 8; ++j) {
        int rel = it + 2 * j + half;
        float w = (rel < deg) ? __int_as_float(ed[j].y) : 0.0f;
        ax[j & 3] += w * __int_as_float(uu[j] << 16);
        ay[j & 3] += w * __int_as_float(uu[j] & 0xffff0000u);
      }
    }
  }
  float sx2 = (ax[0] + ax[1]) + (ax[2] + ax[3]);
  float sy2 = (ay[0] + ay[1]) + (ay[2] + ay[3]);
  sx2 += __shfl_xor(sx2, 32, 64);
  sy2 += __shfl_xor(sy2, 32, 64);
  float2 bv = *(const float2*)&bias[col];
  float vx = sx2 + bv.x, vy = sy2 + bv.y;

  bool valid = (hl < 20);
  float m = valid ? fmaxf(vx, vy) : -INFINITY;
#pragma unroll
  for (int d = 32; d; d >>= 1) m = fmaxf(m, __shfl_xor(m, d, 64));
  float ex = valid ? (expf(vx - m) + expf(vy - m)) : 0.0f;
  float s = ex;
#pragma unroll
  for (int d = 32; d; d >>= 1) s += __shfl_xor(s, d, 64);
  float ls = logf(s);
  if (half == 0 && valid)
    *(float2*)&out[(size_t)wid * NCLASS + hl * 2] = make_float2(vx - m - ls, vy - m - ls);
}

extern "C" void kernel_launch(void* const* d_in, const int* in_sizes, int n_in,
                              void* d_out, int out_size, void* d_ws, size_t ws_size,
                              hipStream_t stream) {
  const float* x   = (const float*)d_in[0];
  const int*   src = (const int*)d_in[1];
  const int*   dst = (const int*)d_in[2];
  const float* ew  = (const float*)d_in[3];
  const float* W[7]; const float* b[7];
  for (int i = 0; i < 7; ++i) {
    W[i] = (const float*)d_in[4 + 2 * i];
    b[i] = (const float*)d_in[5 + 2 * i];
  }
  int N = in_sizes[0] / NFEAT;   // 65536
  int E = in_sizes[1];           // 1048576

  char* ws = (char*)d_ws;
  int*      off     = (int*)(ws + 0);                 // (N+1) ints
  int*      bsum    = (int*)(ws + (1ll << 20));       // 256 ints
  int*      cnt4    = (int*)(ws + (2ll << 20));       // 4N ints = 1MB [2,3)
  int4*     sb4     = (int4*)(ws + (3ll << 20));      // N int4 = 1MB  [3,4)
  int2*     edata   = (int2*)(ws + (4ll << 20));      // E int2 = 8MB  [4,12)
  int*      rank    = (int*)(ws + (12ll << 20));      // E ints = 4MB  [12,16)
  ushort_t* support = (ushort_t*)(ws + (16ll << 20)); // N*64 bf16 = 8MB [16,24)
  float*    hA      = (float*)(ws + (32ll << 20));    // 16MB
  float*    hB      = (float*)(ws + (48ll << 20));    // 16MB

  // ---- build dst-CSR ----
  (void)hipMemsetAsync(cnt4, 0, (size_t)4 * N * sizeof(int), stream);
  rank_k<<<(E / 4 + 255) / 256, 256, 0, stream>>>(dst, cnt4, rank, E, N);
  int nb = (N + 255) / 256;  // 256 blocks
  scan1_k<<<nb, 256, 0, stream>>>(cnt4, off, bsum, sb4, N);
  scan2_k<<<1, 256, 0, stream>>>(bsum, nb);
  scan3_k<<<nb, 256, 0, stream>>>(off, bsum, N, E);
  fill_k<<<(E + 255) / 256, 256, 0, stream>>>(src, dst, ew, off, rank,
                                              (const int*)sb4, edata, E);

  int gb_gemm = N / 64;  // 1024 blocks
  int gb_agg  = N / 4;   // 4 waves per 256-thread block

  // L1: x[128] -> 64, relu
  gemm_k<128, 64><<<gb_gemm, 256, 0, stream>>>(x, W[0], support, N);
  agg_k<<<gb_agg, 256, 0, stream>>>(support, edata, off, b[0], nullptr, hA, N, 1);
  // L2
  gemm_k<64, 64><<<gb_gemm, 256, 0, stream>>>(hA, W[1], support, N);
  agg_k<<<gb_agg, 256, 0, stream>>>(support, edata, off, b[1], nullptr, hB, N, 1);
  // L3: + residual (h2 = hB)
  gemm_k<64, 64><<<gb_gemm, 256, 0, stream>>>(hB, W[2], support, N);
  agg_k<<<gb_agg, 256, 0, stream>>>(support, edata, off, b[2], hB, hA, N, 1);
  // L4: + residual (h3 = hA)
  gemm_k<64, 64><<<gb_gemm, 256, 0, stream>>>(hA, W[3], support, N);
  agg_k<<<gb_agg, 256, 0, stream>>>(support, edata, off, b[3], hA, hB, N, 1);
  // L5: + residual (h4 = hB)
  gemm_k<64, 64><<<gb_gemm, 256, 0, stream>>>(hB, W[4], support, N);
  agg_k<<<gb_agg, 256, 0, stream>>>(support, edata, off, b[4], hB, hA, N, 1);
  // L6
  gemm_k<64, 64><<<gb_gemm, 256, 0, stream>>>(hA, W[5], support, N);
  agg_k<<<gb_agg, 256, 0, stream>>>(support, edata, off, b[5], nullptr, hB, N, 1);
  // L7: 64 -> 40, + log_softmax
  gemm_k<64, 40><<<gb_gemm, 256, 0, stream>>>(hB, W[6], support, N);
  agg_final_k<<<gb_agg, 256, 0, stream>>>(support, edata, off, b[6], (float*)d_out, N);
}

// Round 10
// 403.416 us; speedup vs baseline: 1.0205x; 1.0205x over previous
//
#include <hip/hip_runtime.h>
#include <math.h>

// GCN: 7 graph-conv layers. N=65536 nodes, E=1048576 edges, feat 128->64(x6)->40.
// dst-CSR once per call; per layer {register-blocked GEMM -> bf16 support,
// pull-aggregate: 2 nodes/wave, flat-issue 2x16 gathers in flight, f32 accum}.

constexpr int NFEAT = 128, NHID = 64, NCLASS = 40;

typedef unsigned short ushort_t;
typedef int ivec4 __attribute__((ext_vector_type(4)));   // native vec for nt-store

__device__ inline float bf2f(ushort_t u) {
  union { unsigned int i; float f; } v; v.i = ((unsigned int)u) << 16; return v.f;
}
__device__ inline ushort_t f2bf(float f) {  // round-to-nearest-even
  union { float f; unsigned int i; } v; v.f = f;
  unsigned int lsb = (v.i >> 16) & 1u;
  v.i += 0x7fffu + lsb;
  return (ushort_t)(v.i >> 16);
}

// Histogram + per-edge rank. 4 sub-histograms; rank encodes (subrank<<2)|s.
// (R9: at device-atomic rate floor ~25G/s; spread kept, not the limiter.)
__global__ void rank_k(const int* __restrict__ dst, int* __restrict__ cnt4,
                       int* __restrict__ rank, int E, int N) {
  int i = blockIdx.x * blockDim.x + threadIdx.x;
  int base = i * 4;
  if (base >= E) return;
  int4 d4 = *(const int4*)(dst + base);   // E % 4 == 0
  int r0 = atomicAdd(&cnt4[0 * N + d4.x], 1);
  int r1 = atomicAdd(&cnt4[1 * N + d4.y], 1);
  int r2 = atomicAdd(&cnt4[2 * N + d4.z], 1);
  int r3 = atomicAdd(&cnt4[3 * N + d4.w], 1);
  ivec4 rr = { (r0 << 2) | 0, (r1 << 2) | 1, (r2 << 2) | 2, (r3 << 2) | 3 };
  __builtin_nontemporal_store(rr, (ivec4*)(rank + base));
}

// Block scan of per-node totals; also emits per-node sub-bases sb4.
__global__ void scan1_k(const int* __restrict__ cnt4, int* __restrict__ off,
                        int* __restrict__ bsum, int4* __restrict__ sb4, int n) {
  __shared__ int tmp[256];
  int tid = threadIdx.x;
  int i = blockIdx.x * 256 + tid;
  int c0 = 0, c1 = 0, c2 = 0, c3 = 0;
  if (i < n) {
    c0 = cnt4[i]; c1 = cnt4[n + i]; c2 = cnt4[2 * n + i]; c3 = cnt4[3 * n + i];
  }
  int v = c0 + c1 + c2 + c3;
  tmp[tid] = v;
  __syncthreads();
  for (int d = 1; d < 256; d <<= 1) {
    int t = (tid >= d) ? tmp[tid - d] : 0;
    __syncthreads();
    tmp[tid] += t;
    __syncthreads();
  }
  if (i < n) {
    off[i] = tmp[tid] - v;  // exclusive (within block)
    sb4[i] = make_int4(0, c0, c0 + c1, c0 + c1 + c2);
  }
  if (tid == 255) bsum[blockIdx.x] = tmp[255];
}

__global__ void scan2_k(int* __restrict__ bsum, int nb) {
  __shared__ int tmp[256];
  int tid = threadIdx.x;
  int v = (tid < nb) ? bsum[tid] : 0;
  tmp[tid] = v;
  __syncthreads();
  for (int d = 1; d < 256; d <<= 1) {
    int t = (tid >= d) ? tmp[tid - d] : 0;
    __syncthreads();
    tmp[tid] += t;
    __syncthreads();
  }
  if (tid < nb) bsum[tid] = tmp[tid] - v;  // exclusive
}

__global__ void scan3_k(int* __restrict__ off, const int* __restrict__ bsum, int n, int E) {
  int i = blockIdx.x * blockDim.x + threadIdx.x;
  if (i < n) off[i] += bsum[i >> 8];
  if (i == 0) off[n] = E;
}

// Atomic-free scatter, 4 independent edges per thread for latency hiding.
__global__ void fill_k(const int* __restrict__ src, const int* __restrict__ dst,
                       const float* __restrict__ w, const int* __restrict__ off,
                       const int* __restrict__ rank, const int* __restrict__ sb4,
                       int2* __restrict__ edata, int E) {
  int i = blockIdx.x * blockDim.x + threadIdx.x;
  int base = i * 4;
  if (base >= E) return;
  int4 s4 = *(const int4*)(src + base);
  int4 d4 = *(const int4*)(dst + base);
  float4 w4 = *(const float4*)(w + base);
  int4 r4 = *(const int4*)(rank + base);
  int dd[4] = { d4.x, d4.y, d4.z, d4.w };
  int rr[4] = { r4.x, r4.y, r4.z, r4.w };
  int ss[4] = { s4.x, s4.y, s4.z, s4.w };
  float ww[4] = { w4.x, w4.y, w4.z, w4.w };
  int ob[4], sb[4];
#pragma unroll
  for (int k = 0; k < 4; ++k) ob[k] = off[dd[k]];
#pragma unroll
  for (int k = 0; k < 4; ++k) sb[k] = sb4[dd[k] * 4 + (rr[k] & 3)];
#pragma unroll
  for (int k = 0; k < 4; ++k) {
    int pos = ob[k] + sb[k] + (rr[k] >> 2);
    int2 v = make_int2(ss[k], __float_as_int(ww[k]));
    __builtin_nontemporal_store(*(const long long*)&v, (long long*)&edata[pos]);
  }
}

// Register-blocked GEMM: 64x64 tile / 256-thread block, 4x4 per thread.
// Output written as bf16 (support tables).
template<int FI, int FO>
__global__ __launch_bounds__(256) void gemm_k(const float* __restrict__ h,
                                              const float* __restrict__ W,
                                              ushort_t* __restrict__ out, int n) {
  constexpr int HS = 68;            // h_lds row stride, pad 4
  __shared__ float hl[64 * HS];     // 17408 B
  __shared__ float wl[64 * 64];     // 16384 B
  int tid = threadIdx.x;
  int row0 = blockIdx.x * 64;
  int tx = tid & 15, ty = tid >> 4;

  float acc[4][4] = {};

  for (int kc = 0; kc < FI; kc += 64) {
    {
      const float* hb = h + (size_t)row0 * FI + kc;
      for (int i = tid; i < 64 * 16; i += 256) {
        int r = i >> 4, kk = (i & 15) << 2;
        float4 v = *(const float4*)(hb + (size_t)r * FI + kk);
        *(float4*)&hl[r * HS + kk] = v;
      }
    }
    if (FO == 64) {
      const float4* Wb = (const float4*)(W + (size_t)kc * 64);
      for (int i = tid; i < 64 * 16; i += 256) ((float4*)wl)[i] = Wb[i];
    } else {
      for (int i = tid; i < 64 * 64; i += 256) wl[i] = 0.0f;
      __syncthreads();
      for (int i = tid; i < 64 * FO; i += 256)
        wl[(i / FO) * 64 + (i % FO)] = W[(size_t)(kc + i / FO) * FO + (i % FO)];
    }
    __syncthreads();

    for (int k4 = 0; k4 < 64; k4 += 4) {
      float4 a[4];
#pragma unroll
      for (int r = 0; r < 4; ++r)
        a[r] = *(const float4*)&hl[(ty * 4 + r) * HS + k4];
#pragma unroll
      for (int j = 0; j < 4; ++j) {
        float4 bv = *(const float4*)&wl[(k4 + j) * 64 + tx * 4];
        const float* bp = (const float*)&bv;
#pragma unroll
        for (int r = 0; r < 4; ++r) {
          const float* ap = (const float*)&a[r];
#pragma unroll
          for (int c = 0; c < 4; ++c) acc[r][c] += ap[j] * bp[c];
        }
      }
    }
    __syncthreads();
  }

  if (FO == 64) {
#pragma unroll
    for (int r = 0; r < 4; ++r) {
      ushort_t pk[4];
#pragma unroll
      for (int c = 0; c < 4; ++c) pk[c] = f2bf(acc[r][c]);
      *(ushort4*)&out[(size_t)(row0 + ty * 4 + r) * 64 + tx * 4] =
          make_ushort4(pk[0], pk[1], pk[2], pk[3]);
    }
  } else {
#pragma unroll
    for (int r = 0; r < 4; ++r)
#pragma unroll
      for (int c = 0; c < 4; ++c) {
        int col = tx * 4 + c;
        if (col < FO) out[(size_t)(row0 + ty * 4 + r) * FO + col] = f2bf(acc[r][c]);
      }
  }
}

// Pull aggregation: TWO nodes per wave. Per node, lanes 0-31 = even edges,
// 32-63 = odd edges; lane loads 2 bf16 feats per gather. Both nodes' flat
// 16-gather bodies are independent -> ~32 gathers in flight per wave,
// halving the serial latency rounds per CU.
__global__ __launch_bounds__(256, 4) void agg_k(
    const ushort_t* __restrict__ support,
    const int2* __restrict__ edata,
    const int* __restrict__ off,
    const float* __restrict__ bias,
    const float* __restrict__ resid,
    float* __restrict__ out,
    int n, int do_relu) {
  int tid = blockIdx.x * blockDim.x + threadIdx.x;
  int p = tid >> 6, lane = tid & 63;
  int nA = 2 * p, nB = 2 * p + 1;
  if (nA >= n) return;
  int half = lane >> 5;   // which edge of the pair
  int hl   = lane & 31;   // feature pair (feats 2hl, 2hl+1)
  int e0a = __builtin_amdgcn_readfirstlane(off[nA]);
  int e0b = __builtin_amdgcn_readfirstlane(off[nB]);
  int e1b = __builtin_amdgcn_readfirstlane(off[nB + 1]);
  int degA = e0b - e0a, degB = e1b - e0b;

  const ushort_t* sp = support + hl * 2;       // per-lane feature base
  const int* epA = (const int*)(edata + e0a);
  const int* epB = (const int*)(edata + e0b);

  float axA[4] = {}, ayA[4] = {}, axB[4] = {}, ayB[4] = {};

  // ---- flat bodies: issue A's and B's src loads, then all 32 gathers ----
  int sA[16], sB[16];
#pragma unroll
  for (int j = 0; j < 16; ++j) {
    int rel = 2 * j + half;
    sA[j] = epA[(rel < degA ? rel : 0) * 2];
  }
#pragma unroll
  for (int j = 0; j < 16; ++j) {
    int rel = 2 * j + half;
    sB[j] = epB[(rel < degB ? rel : 0) * 2];
  }
  unsigned int uA[16], uB[16];
#pragma unroll
  for (int j = 0; j < 16; ++j)
    uA[j] = *(const unsigned int*)(sp + ((size_t)sA[j] << 6));
#pragma unroll
  for (int j = 0; j < 16; ++j)
    uB[j] = *(const unsigned int*)(sp + ((size_t)sB[j] << 6));
#pragma unroll
  for (int j = 0; j < 16; ++j) {
    int rel = 2 * j + half;
    float w = (rel < degA) ? __int_as_float(epA[rel * 2 + 1]) : 0.0f;
    axA[j & 3] += w * __int_as_float(uA[j] << 16);
    ayA[j & 3] += w * __int_as_float(uA[j] & 0xffff0000u);
  }
#pragma unroll
  for (int j = 0; j < 16; ++j) {
    int rel = 2 * j + half;
    float w = (rel < degB) ? __int_as_float(epB[rel * 2 + 1]) : 0.0f;
    axB[j & 3] += w * __int_as_float(uB[j] << 16);
    ayB[j & 3] += w * __int_as_float(uB[j] & 0xffff0000u);
  }
  // ---- rare remainder (deg > 32): masked 16-edge chunks, per node ----
  for (int it = 32; it < degA; it += 16) {
    int2 ed[8];
#pragma unroll
    for (int j = 0; j < 8; ++j) {
      int rel = it + 2 * j + half;
      ed[j] = *(const int2*)(epA + (rel < degA ? rel : 0) * 2);
    }
    unsigned int uu[8];
#pragma unroll
    for (int j = 0; j < 8; ++j)
      uu[j] = *(const unsigned int*)(sp + ((size_t)ed[j].x << 6));
#pragma unroll
    for (int j = 0; j < 8; ++j) {
      int rel = it + 2 * j + half;
      float w = (rel < degA) ? __int_as_float(ed[j].y) : 0.0f;
      axA[j & 3] += w * __int_as_float(uu[j] << 16);
      ayA[j & 3] += w * __int_as_float(uu[j] & 0xffff0000u);
    }
  }
  for (int it = 32; it < degB; it += 16) {
    int2 ed[8];
#pragma unroll
    for (int j = 0; j < 8; ++j) {
      int rel = it + 2 * j + half;
      ed[j] = *(const int2*)(epB + (rel < degB ? rel : 0) * 2);
    }
    unsigned int uu[8];
#pragma unroll
    for (int j = 0; j < 8; ++j)
      uu[j] = *(const unsigned int*)(sp + ((size_t)ed[j].x << 6));
#pragma unroll
    for (int j = 0; j < 8; ++j) {
      int rel = it + 2 * j + half;
      float w = (rel < degB) ? __int_as_float(ed[j].y) : 0.0f;
      axB[j & 3] += w * __int_as_float(uu[j] << 16);
      ayB[j & 3] += w * __int_as_float(uu[j] & 0xffff0000u);
    }
  }

  float sxA = ((axA[0] + axA[1]) + (axA[2] + axA[3]));
  float syA = ((ayA[0] + ayA[1]) + (ayA[2] + ayA[3]));
  float sxB = ((axB[0] + axB[1]) + (axB[2] + axB[3]));
  float syB = ((ayB[0] + ayB[1]) + (ayB[2] + ayB[3]));
  sxA += __shfl_xor(sxA, 32, 64);
  syA += __shfl_xor(syA, 32, 64);
  sxB += __shfl_xor(sxB, 32, 64);
  syB += __shfl_xor(syB, 32, 64);

  float2 bv = *(const float2*)&bias[hl * 2];
  if (half == 0) {   // lanes 0-31 write node A
    float vx = sxA + bv.x, vy = syA + bv.y;
    if (do_relu) { vx = fmaxf(vx, 0.0f); vy = fmaxf(vy, 0.0f); }
    if (resid) {
      float2 r = *(const float2*)&resid[(size_t)nA * 64 + hl * 2];
      vx += r.x; vy += r.y;
    }
    *(float2*)&out[(size_t)nA * 64 + hl * 2] = make_float2(vx, vy);
  } else {           // lanes 32-63 write node B
    float vx = sxB + bv.x, vy = syB + bv.y;
    if (do_relu) { vx = fmaxf(vx, 0.0f); vy = fmaxf(vy, 0.0f); }
    if (resid) {
      float2 r = *(const float2*)&resid[(size_t)nB * 64 + hl * 2];
      vx += r.x; vy += r.y;
    }
    *(float2*)&out[(size_t)nB * 64 + hl * 2] = make_float2(vx, vy);
  }
}

// Final layer: FO=40, two nodes per wave, then bias + log_softmax per node.
// Softmax denominator: exp terms contributed from ONE half only (fixes the
// prior 2x double-count; max is duplicate-immune).
__global__ __launch_bounds__(256, 4) void agg_final_k(
    const ushort_t* __restrict__ support,
    const int2* __restrict__ edata,
    const int* __restrict__ off,
    const float* __restrict__ bias,
    float* __restrict__ out, int n) {
  int tid = blockIdx.x * blockDim.x + threadIdx.x;
  int p = tid >> 6, lane = tid & 63;
  int nA = 2 * p, nB = 2 * p + 1;
  if (nA >= n) return;
  int half = lane >> 5;
  int hl   = lane & 31;
  int col  = (hl < 20 ? hl : 0) * 2;   // clamp to stay in-row
  int e0a = __builtin_amdgcn_readfirstlane(off[nA]);
  int e0b = __builtin_amdgcn_readfirstlane(off[nB]);
  int e1b = __builtin_amdgcn_readfirstlane(off[nB + 1]);
  int degA = e0b - e0a, degB = e1b - e0b;

  const ushort_t* sp = support + col;
  const int* epA = (const int*)(edata + e0a);
  const int* epB = (const int*)(edata + e0b);

  float axA[4] = {}, ayA[4] = {}, axB[4] = {}, ayB[4] = {};

  int sA[16], sB[16];
#pragma unroll
  for (int j = 0; j < 16; ++j) {
    int rel = 2 * j + half;
    sA[j] = epA[(rel < degA ? rel : 0) * 2];
  }
#pragma unroll
  for (int j = 0; j < 16; ++j) {
    int rel = 2 * j + half;
    sB[j] = epB[(rel < degB ? rel : 0) * 2];
  }
  unsigned int uA[16], uB[16];
#pragma unroll
  for (int j = 0; j < 16; ++j)
    uA[j] = *(const unsigned int*)(sp + (size_t)sA[j] * NCLASS);
#pragma unroll
  for (int j = 0; j < 16; ++j)
    uB[j] = *(const unsigned int*)(sp + (size_t)sB[j] * NCLASS);
#pragma unroll
  for (int j = 0; j < 16; ++j) {
    int rel = 2 * j + half;
    float w = (rel < degA) ? __int_as_float(epA[rel * 2 + 1]) : 0.0f;
    axA[j & 3] += w * __int_as_float(uA[j] << 16);
    ayA[j & 3] += w * __int_as_float(uA[j] & 0xffff0000u);
  }
#pragma unroll
  for (int j = 0; j < 16; ++j) {
    int rel = 2 * j + half;
    float w = (rel < degB) ? __int_as_float(epB[rel * 2 + 1]) : 0.0f;
    axB[j & 3] += w * __int_as_float(uB[j] << 16);
    ayB[j & 3] += w * __int_as_float(uB[j] & 0xffff0000u);
  }
  for (int it = 32; it < degA; it += 16) {
    int2 ed[8];
#pragma unroll
    for (int j = 0; j < 8; ++j) {
      int rel = it + 2 * j + half;
      ed[j] = *(const int2*)(epA + (rel < degA ? rel : 0) * 2);
    }
    unsigned int uu[8];
#pragma unroll
    for (int j = 0; j < 8; ++j)
      uu[j] = *(const unsigned int*)(sp + (size_t)ed[j].x * NCLASS);
#pragma unroll
    for (int j = 0; j < 8; ++j) {
      int rel = it + 2 * j + half;
      float w = (rel < degA) ? __int_as_float(ed[j].y) : 0.0f;
      axA[j & 3] += w * __int_as_float(uu[j] << 16);
      ayA[j & 3] += w * __int_as_float(uu[j] & 0xffff0000u);
    }
  }
  for (int it = 32; it < degB; it += 16) {
    int2 ed[8];
#pragma unroll
    for (int j = 0; j < 8; ++j) {
      int rel = it + 2 * j + half;
      ed[j] = *(const int2*)(epB + (rel < degB ? rel : 0) * 2);
    }
    unsigned int uu[8];
#pragma unroll
    for (int j = 0; j < 8; ++j)
      uu[j] = *(const unsigned int*)(sp + (size_t)ed[j].x * NCLASS);
#pragma unroll
    for (int j = 0; j < 8; ++j) {
      int rel = it + 2 * j + half;
      float w = (rel < degB) ? __int_as_float(ed[j].y) : 0.0f;
      axB[j & 3] += w * __int_as_float(uu[j] << 16);
      ayB[j & 3] += w * __int_as_float(uu[j] & 0xffff0000u);
    }
  }

  float sxA = ((axA[0] + axA[1]) + (axA[2] + axA[3]));
  float syA = ((ayA[0] + ayA[1]) + (ayA[2] + ayA[3]));
  float sxB = ((axB[0] + axB[1]) + (axB[2] + axB[3]));
  float syB = ((ayB[0] + ayB[1]) + (ayB[2] + ayB[3]));
  sxA += __shfl_xor(sxA, 32, 64);
  syA += __shfl_xor(syA, 32, 64);
  sxB += __shfl_xor(sxB, 32, 64);
  syB += __shfl_xor(syB, 32, 64);

  bool valid = (hl < 20);
  float2 bv = *(const float2*)&bias[col];
  float vxA = sxA + bv.x, vyA = syA + bv.y;
  float vxB = sxB + bv.x, vyB = syB + bv.y;

  // max (duplicate-immune across halves)
  float mA = valid ? fmaxf(vxA, vyA) : -INFINITY;
  float mB = valid ? fmaxf(vxB, vyB) : -INFINITY;
#pragma unroll
  for (int d = 32; d; d >>= 1) {
    mA = fmaxf(mA, __shfl_xor(mA, d, 64));
    mB = fmaxf(mB, __shfl_xor(mB, d, 64));
  }
  // denom: contribute from one half only (no double count)
  float exA = (valid && half == 0) ? (expf(vxA - mA) + expf(vyA - mA)) : 0.0f;
  float exB = (valid && half == 0) ? (expf(vxB - mB) + expf(vyB - mB)) : 0.0f;
  float sA2 = exA, sB2 = exB;
#pragma unroll
  for (int d = 32; d; d >>= 1) {
    sA2 += __shfl_xor(sA2, d, 64);
    sB2 += __shfl_xor(sB2, d, 64);
  }
  if (valid) {
    if (half == 0) {
      float ls = logf(sA2);
      *(float2*)&out[(size_t)nA * NCLASS + hl * 2] =
          make_float2(vxA - mA - ls, vyA - mA - ls);
    } else {
      float ls = logf(sB2);
      *(float2*)&out[(size_t)nB * NCLASS + hl * 2] =
          make_float2(vxB - mB - ls, vyB - mB - ls);
    }
  }
}

extern "C" void kernel_launch(void* const* d_in, const int* in_sizes, int n_in,
                              void* d_out, int out_size, void* d_ws, size_t ws_size,
                              hipStream_t stream) {
  const float* x   = (const float*)d_in[0];
  const int*   src = (const int*)d_in[1];
  const int*   dst = (const int*)d_in[2];
  const float* ew  = (const float*)d_in[3];
  const float* W[7]; const float* b[7];
  for (int i = 0; i < 7; ++i) {
    W[i] = (const float*)d_in[4 + 2 * i];
    b[i] = (const float*)d_in[5 + 2 * i];
  }
  int N = in_sizes[0] / NFEAT;   // 65536
  int E = in_sizes[1];           // 1048576

  char* ws = (char*)d_ws;
  int*      off     = (int*)(ws + 0);                 // (N+1) ints
  int*      bsum    = (int*)(ws + (1ll << 20));       // 256 ints
  int*      cnt4    = (int*)(ws + (2ll << 20));       // 4N ints = 1MB [2,3)
  int4*     sb4     = (int4*)(ws + (3ll << 20));      // N int4 = 1MB  [3,4)
  int2*     edata   = (int2*)(ws + (4ll << 20));      // E int2 = 8MB  [4,12)
  int*      rank    = (int*)(ws + (12ll << 20));      // E ints = 4MB  [12,16)
  ushort_t* support = (ushort_t*)(ws + (16ll << 20)); // N*64 bf16 = 8MB [16,24)
  float*    hA      = (float*)(ws + (32ll << 20));    // 16MB
  float*    hB      = (float*)(ws + (48ll << 20));    // 16MB

  // ---- build dst-CSR ----
  (void)hipMemsetAsync(cnt4, 0, (size_t)4 * N * sizeof(int), stream);
  rank_k<<<(E / 4 + 255) / 256, 256, 0, stream>>>(dst, cnt4, rank, E, N);
  int nb = (N + 255) / 256;  // 256 blocks
  scan1_k<<<nb, 256, 0, stream>>>(cnt4, off, bsum, sb4, N);
  scan2_k<<<1, 256, 0, stream>>>(bsum, nb);
  scan3_k<<<nb, 256, 0, stream>>>(off, bsum, N, E);
  fill_k<<<(E / 4 + 255) / 256, 256, 0, stream>>>(src, dst, ew, off, rank,
                                                  (const int*)sb4, edata, E);

  int gb_gemm = N / 64;  // 1024 blocks
  int gb_agg  = N / 8;   // 2 nodes/wave, 4 waves per 256-thread block

  // L1: x[128] -> 64, relu
  gemm_k<128, 64><<<gb_gemm, 256, 0, stream>>>(x, W[0], support, N);
  agg_k<<<gb_agg, 256, 0, stream>>>(support, edata, off, b[0], nullptr, hA, N, 1);
  // L2
  gemm_k<64, 64><<<gb_gemm, 256, 0, stream>>>(hA, W[1], support, N);
  agg_k<<<gb_agg, 256, 0, stream>>>(support, edata, off, b[1], nullptr, hB, N, 1);
  // L3: + residual (h2 = hB)
  gemm_k<64, 64><<<gb_gemm, 256, 0, stream>>>(hB, W[2], support, N);
  agg_k<<<gb_agg, 256, 0, stream>>>(support, edata, off, b[2], hB, hA, N, 1);
  // L4: + residual (h3 = hA)
  gemm_k<64, 64><<<gb_gemm, 256, 0, stream>>>(hA, W[3], support, N);
  agg_k<<<gb_agg, 256, 0, stream>>>(support, edata, off, b[3], hA, hB, N, 1);
  // L5: + residual (h4 = hB)
  gemm_k<64, 64><<<gb_gemm, 256, 0, stream>>>(hB, W[4], support, N);
  agg_k<<<gb_agg, 256, 0, stream>>>(support, edata, off, b[4], hB, hA, N, 1);
  // L6
  gemm_k<64, 64><<<gb_gemm, 256, 0, stream>>>(hA, W[5], support, N);
  agg_k<<<gb_agg, 256, 0, stream>>>(support, edata, off, b[5], nullptr, hB, N, 1);
  // L7: 64 -> 40, + log_softmax
  gemm_k<64, 40><<<gb_gemm, 256, 0, stream>>>(hB, W[6], support, N);
  agg_final_k<<<gb_agg, 256, 0, stream>>>(support, edata, off, b[6], (float*)d_out, N);
}

// Round 11
// 386.788 us; speedup vs baseline: 1.0644x; 1.0430x over previous
//
#include <hip/hip_runtime.h>
#include <math.h>

// GCN: 7 graph-conv layers. N=65536 nodes, E=1048576 edges, feat 128->64(x6)->40.
// dst-CSR once per call; then: gemm1, 6x fused{pull-aggregate + next-layer GEMM},
// final aggregate + log_softmax. Fused GEMM hides under gather latency.

constexpr int NFEAT = 128, NHID = 64, NCLASS = 40;

typedef unsigned short ushort_t;
typedef int ivec4 __attribute__((ext_vector_type(4)));   // native vec for nt-store

__device__ inline float bf2f(ushort_t u) {
  union { unsigned int i; float f; } v; v.i = ((unsigned int)u) << 16; return v.f;
}
__device__ inline ushort_t f2bf(float f) {  // round-to-nearest-even
  union { float f; unsigned int i; } v; v.f = f;
  unsigned int lsb = (v.i >> 16) & 1u;
  v.i += 0x7fffu + lsb;
  return (ushort_t)(v.i >> 16);
}

// Histogram + per-edge rank. 4 sub-histograms; rank encodes (subrank<<2)|s.
// (R9: at device-atomic rate floor; not the limiter to attack further.)
__global__ void rank_k(const int* __restrict__ dst, int* __restrict__ cnt4,
                       int* __restrict__ rank, int E, int N) {
  int i = blockIdx.x * blockDim.x + threadIdx.x;
  int base = i * 4;
  if (base >= E) return;
  int4 d4 = *(const int4*)(dst + base);   // E % 4 == 0
  int r0 = atomicAdd(&cnt4[0 * N + d4.x], 1);
  int r1 = atomicAdd(&cnt4[1 * N + d4.y], 1);
  int r2 = atomicAdd(&cnt4[2 * N + d4.z], 1);
  int r3 = atomicAdd(&cnt4[3 * N + d4.w], 1);
  ivec4 rr = { (r0 << 2) | 0, (r1 << 2) | 1, (r2 << 2) | 2, (r3 << 2) | 3 };
  __builtin_nontemporal_store(rr, (ivec4*)(rank + base));
}

// Block scan of per-node totals; also emits per-node sub-bases sb4.
__global__ void scan1_k(const int* __restrict__ cnt4, int* __restrict__ off,
                        int* __restrict__ bsum, int4* __restrict__ sb4, int n) {
  __shared__ int tmp[256];
  int tid = threadIdx.x;
  int i = blockIdx.x * 256 + tid;
  int c0 = 0, c1 = 0, c2 = 0, c3 = 0;
  if (i < n) {
    c0 = cnt4[i]; c1 = cnt4[n + i]; c2 = cnt4[2 * n + i]; c3 = cnt4[3 * n + i];
  }
  int v = c0 + c1 + c2 + c3;
  tmp[tid] = v;
  __syncthreads();
  for (int d = 1; d < 256; d <<= 1) {
    int t = (tid >= d) ? tmp[tid - d] : 0;
    __syncthreads();
    tmp[tid] += t;
    __syncthreads();
  }
  if (i < n) {
    off[i] = tmp[tid] - v;  // exclusive (within block)
    sb4[i] = make_int4(0, c0, c0 + c1, c0 + c1 + c2);
  }
  if (tid == 255) bsum[blockIdx.x] = tmp[255];
}

__global__ void scan2_k(int* __restrict__ bsum, int nb) {
  __shared__ int tmp[256];
  int tid = threadIdx.x;
  int v = (tid < nb) ? bsum[tid] : 0;
  tmp[tid] = v;
  __syncthreads();
  for (int d = 1; d < 256; d <<= 1) {
    int t = (tid >= d) ? tmp[tid - d] : 0;
    __syncthreads();
    tmp[tid] += t;
    __syncthreads();
  }
  if (tid < nb) bsum[tid] = tmp[tid] - v;  // exclusive
}

__global__ void scan3_k(int* __restrict__ off, const int* __restrict__ bsum, int n, int E) {
  int i = blockIdx.x * blockDim.x + threadIdx.x;
  if (i < n) off[i] += bsum[i >> 8];
  if (i == 0) off[n] = E;
}

// Atomic-free scatter, 4 independent edges per thread for latency hiding.
__global__ void fill_k(const int* __restrict__ src, const int* __restrict__ dst,
                       const float* __restrict__ w, const int* __restrict__ off,
                       const int* __restrict__ rank, const int* __restrict__ sb4,
                       int2* __restrict__ edata, int E) {
  int i = blockIdx.x * blockDim.x + threadIdx.x;
  int base = i * 4;
  if (base >= E) return;
  int4 s4 = *(const int4*)(src + base);
  int4 d4 = *(const int4*)(dst + base);
  float4 w4 = *(const float4*)(w + base);
  int4 r4 = *(const int4*)(rank + base);
  int dd[4] = { d4.x, d4.y, d4.z, d4.w };
  int rr[4] = { r4.x, r4.y, r4.z, r4.w };
  int ss[4] = { s4.x, s4.y, s4.z, s4.w };
  float ww[4] = { w4.x, w4.y, w4.z, w4.w };
  int ob[4], sb[4];
#pragma unroll
  for (int k = 0; k < 4; ++k) ob[k] = off[dd[k]];
#pragma unroll
  for (int k = 0; k < 4; ++k) sb[k] = sb4[dd[k] * 4 + (rr[k] & 3)];
#pragma unroll
  for (int k = 0; k < 4; ++k) {
    int pos = ob[k] + sb[k] + (rr[k] >> 2);
    int2 v = make_int2(ss[k], __float_as_int(ww[k]));
    __builtin_nontemporal_store(*(const long long*)&v, (long long*)&edata[pos]);
  }
}

// Register-blocked GEMM (layer 1 only): 64x64 tile / 256 threads, 4x4/thread.
template<int FI, int FO>
__global__ __launch_bounds__(256) void gemm_k(const float* __restrict__ h,
                                              const float* __restrict__ W,
                                              ushort_t* __restrict__ out, int n) {
  constexpr int HS = 68;
  __shared__ float hl[64 * HS];
  __shared__ float wl[64 * 64];
  int tid = threadIdx.x;
  int row0 = blockIdx.x * 64;
  int tx = tid & 15, ty = tid >> 4;

  float acc[4][4] = {};

  for (int kc = 0; kc < FI; kc += 64) {
    {
      const float* hb = h + (size_t)row0 * FI + kc;
      for (int i = tid; i < 64 * 16; i += 256) {
        int r = i >> 4, kk = (i & 15) << 2;
        float4 v = *(const float4*)(hb + (size_t)r * FI + kk);
        *(float4*)&hl[r * HS + kk] = v;
      }
    }
    {
      const float4* Wb = (const float4*)(W + (size_t)kc * 64);
      for (int i = tid; i < 64 * 16; i += 256) ((float4*)wl)[i] = Wb[i];
    }
    __syncthreads();

    for (int k4 = 0; k4 < 64; k4 += 4) {
      float4 a[4];
#pragma unroll
      for (int r = 0; r < 4; ++r)
        a[r] = *(const float4*)&hl[(ty * 4 + r) * HS + k4];
#pragma unroll
      for (int j = 0; j < 4; ++j) {
        float4 bv = *(const float4*)&wl[(k4 + j) * 64 + tx * 4];
        const float* bp = (const float*)&bv;
#pragma unroll
        for (int r = 0; r < 4; ++r) {
          const float* ap = (const float*)&a[r];
#pragma unroll
          for (int c = 0; c < 4; ++c) acc[r][c] += ap[j] * bp[c];
        }
      }
    }
    __syncthreads();
  }

#pragma unroll
  for (int r = 0; r < 4; ++r) {
    ushort_t pk[4];
#pragma unroll
    for (int c = 0; c < 4; ++c) pk[c] = f2bf(acc[r][c]);
    *(ushort4*)&out[(size_t)(row0 + ty * 4 + r) * 64 + tx * 4] =
        make_ushort4(pk[0], pk[1], pk[2], pk[3]);
  }
}

// Fused pull-aggregate + next-layer GEMM. Two nodes per wave (A: lanes 0-31,
// B: lanes 32-63 for edge parity; each lane owns feature pair 2hl,2hl+1).
// After the gather epilogue each wave holds h for its 2 nodes; it writes h to
// a private LDS slot and computes S_next = h @ Wn against LDS-staged Wn.
// The GEMM VALU/LDS work hides under other waves' gather stalls.
template<int FO, bool WRITE_H>
__global__ __launch_bounds__(256, 4) void aggemm_k(
    const ushort_t* __restrict__ support,   // N x 64 bf16 (layer input S)
    const int2* __restrict__ edata,
    const int* __restrict__ off,
    const float* __restrict__ bias,         // 64
    const float* __restrict__ resid,        // N x 64 f32 or null
    const float* __restrict__ Wn,           // 64 x FO
    ushort_t* __restrict__ sout,            // N x FO bf16 (next layer S)
    float* __restrict__ hout,               // N x 64 f32 (if WRITE_H)
    int n) {
  __shared__ float Wl[64 * FO];
  __shared__ float hls[4][2][64];
  int tid = threadIdx.x;
  for (int i = tid; i < (64 * FO) / 4; i += 256)
    ((float4*)Wl)[i] = ((const float4*)Wn)[i];
  __syncthreads();

  int p = (blockIdx.x * blockDim.x + tid) >> 6, lane = tid & 63;
  int wv = tid >> 6;
  int nA = 2 * p, nB = 2 * p + 1;
  if (nA >= n) return;
  if (nB >= n) nB = n - 1;   // (n even in practice; benign duplicate)
  int half = lane >> 5;
  int hl   = lane & 31;
  int e0a = __builtin_amdgcn_readfirstlane(off[nA]);
  int e0b = __builtin_amdgcn_readfirstlane(off[nB]);
  int e1b = __builtin_amdgcn_readfirstlane(off[nB + 1]);
  int degA = e0b - e0a, degB = e1b - e0b;

  const ushort_t* sp = support + hl * 2;
  const int* epA = (const int*)(edata + e0a);
  const int* epB = (const int*)(edata + e0b);

  float axA[4] = {}, ayA[4] = {}, axB[4] = {}, ayB[4] = {};

  // ---- flat gather bodies: A and B issued back-to-back (32 in flight) ----
  int sA[16], sB[16];
#pragma unroll
  for (int j = 0; j < 16; ++j) {
    int rel = 2 * j + half;
    sA[j] = epA[(rel < degA ? rel : 0) * 2];
  }
#pragma unroll
  for (int j = 0; j < 16; ++j) {
    int rel = 2 * j + half;
    sB[j] = epB[(rel < degB ? rel : 0) * 2];
  }
  unsigned int uA[16], uB[16];
#pragma unroll
  for (int j = 0; j < 16; ++j)
    uA[j] = *(const unsigned int*)(sp + ((size_t)sA[j] << 6));
#pragma unroll
  for (int j = 0; j < 16; ++j)
    uB[j] = *(const unsigned int*)(sp + ((size_t)sB[j] << 6));
#pragma unroll
  for (int j = 0; j < 16; ++j) {
    int rel = 2 * j + half;
    float w = (rel < degA) ? __int_as_float(epA[rel * 2 + 1]) : 0.0f;
    axA[j & 3] += w * __int_as_float(uA[j] << 16);
    ayA[j & 3] += w * __int_as_float(uA[j] & 0xffff0000u);
  }
#pragma unroll
  for (int j = 0; j < 16; ++j) {
    int rel = 2 * j + half;
    float w = (rel < degB) ? __int_as_float(epB[rel * 2 + 1]) : 0.0f;
    axB[j & 3] += w * __int_as_float(uB[j] << 16);
    ayB[j & 3] += w * __int_as_float(uB[j] & 0xffff0000u);
  }
  // ---- rare remainder (deg > 32) ----
  for (int it = 32; it < degA; it += 16) {
    int2 ed[8];
#pragma unroll
    for (int j = 0; j < 8; ++j) {
      int rel = it + 2 * j + half;
      ed[j] = *(const int2*)(epA + (rel < degA ? rel : 0) * 2);
    }
    unsigned int uu[8];
#pragma unroll
    for (int j = 0; j < 8; ++j)
      uu[j] = *(const unsigned int*)(sp + ((size_t)ed[j].x << 6));
#pragma unroll
    for (int j = 0; j < 8; ++j) {
      int rel = it + 2 * j + half;
      float w = (rel < degA) ? __int_as_float(ed[j].y) : 0.0f;
      axA[j & 3] += w * __int_as_float(uu[j] << 16);
      ayA[j & 3] += w * __int_as_float(uu[j] & 0xffff0000u);
    }
  }
  for (int it = 32; it < degB; it += 16) {
    int2 ed[8];
#pragma unroll
    for (int j = 0; j < 8; ++j) {
      int rel = it + 2 * j + half;
      ed[j] = *(const int2*)(epB + (rel < degB ? rel : 0) * 2);
    }
    unsigned int uu[8];
#pragma unroll
    for (int j = 0; j < 8; ++j)
      uu[j] = *(const unsigned int*)(sp + ((size_t)ed[j].x << 6));
#pragma unroll
    for (int j = 0; j < 8; ++j) {
      int rel = it + 2 * j + half;
      float w = (rel < degB) ? __int_as_float(ed[j].y) : 0.0f;
      axB[j & 3] += w * __int_as_float(uu[j] << 16);
      ayB[j & 3] += w * __int_as_float(uu[j] & 0xffff0000u);
    }
  }

  float sxA = ((axA[0] + axA[1]) + (axA[2] + axA[3]));
  float syA = ((ayA[0] + ayA[1]) + (ayA[2] + ayA[3]));
  float sxB = ((axB[0] + axB[1]) + (axB[2] + axB[3]));
  float syB = ((ayB[0] + ayB[1]) + (ayB[2] + ayB[3]));
  sxA += __shfl_xor(sxA, 32, 64);
  syA += __shfl_xor(syA, 32, 64);
  sxB += __shfl_xor(sxB, 32, 64);
  syB += __shfl_xor(syB, 32, 64);

  // ---- h epilogue: bias, relu, residual; write h to LDS (+global if needed) ----
  int node = (half == 0) ? nA : nB;
  float2 bv = *(const float2*)&bias[hl * 2];
  float vx = ((half == 0) ? sxA : sxB) + bv.x;
  float vy = ((half == 0) ? syA : syB) + bv.y;
  vx = fmaxf(vx, 0.0f); vy = fmaxf(vy, 0.0f);
  if (resid) {
    float2 r = *(const float2*)&resid[(size_t)node * 64 + hl * 2];
    vx += r.x; vy += r.y;
  }
  if (WRITE_H)
    *(float2*)&hout[(size_t)node * 64 + hl * 2] = make_float2(vx, vy);
  *(float2*)&hls[wv][half][hl * 2] = make_float2(vx, vy);
  __threadfence_block();   // drain ds_write before cross-lane ds_read (same wave)

  // ---- fused GEMM: S_next[node][2hl,2hl+1] = h[node] @ Wn ----
  int col2 = (2 * hl < FO) ? 2 * hl : 0;   // clamp for FO=40 inactive lanes
  const float* hb = hls[wv][half];
  float ox0 = 0.f, ox1 = 0.f, oy0 = 0.f, oy1 = 0.f;
#pragma unroll
  for (int k = 0; k < 64; k += 4) {
    float4 hv = *(const float4*)&hb[k];   // broadcast within half
    float2 w0 = *(const float2*)&Wl[(k + 0) * FO + col2];
    float2 w1 = *(const float2*)&Wl[(k + 1) * FO + col2];
    float2 w2 = *(const float2*)&Wl[(k + 2) * FO + col2];
    float2 w3 = *(const float2*)&Wl[(k + 3) * FO + col2];
    ox0 += hv.x * w0.x; oy0 += hv.x * w0.y;
    ox1 += hv.y * w1.x; oy1 += hv.y * w1.y;
    ox0 += hv.z * w2.x; oy0 += hv.z * w2.y;
    ox1 += hv.w * w3.x; oy1 += hv.w * w3.y;
  }
  float ox = ox0 + ox1, oy = oy0 + oy1;
  unsigned int pk = (unsigned int)f2bf(ox) | ((unsigned int)f2bf(oy) << 16);
  if (2 * hl < FO)
    *(unsigned int*)&sout[(size_t)node * FO + 2 * hl] = pk;
}

// Final layer: FO=40 aggregation + bias + log_softmax, two nodes per wave.
__global__ __launch_bounds__(256, 4) void agg_final_k(
    const ushort_t* __restrict__ support,
    const int2* __restrict__ edata,
    const int* __restrict__ off,
    const float* __restrict__ bias,
    float* __restrict__ out, int n) {
  int tid = blockIdx.x * blockDim.x + threadIdx.x;
  int p = tid >> 6, lane = tid & 63;
  int nA = 2 * p, nB = 2 * p + 1;
  if (nA >= n) return;
  if (nB >= n) nB = n - 1;
  int half = lane >> 5;
  int hl   = lane & 31;
  int col  = (hl < 20 ? hl : 0) * 2;
  int e0a = __builtin_amdgcn_readfirstlane(off[nA]);
  int e0b = __builtin_amdgcn_readfirstlane(off[nB]);
  int e1b = __builtin_amdgcn_readfirstlane(off[nB + 1]);
  int degA = e0b - e0a, degB = e1b - e0b;

  const ushort_t* sp = support + col;
  const int* epA = (const int*)(edata + e0a);
  const int* epB = (const int*)(edata + e0b);

  float axA[4] = {}, ayA[4] = {}, axB[4] = {}, ayB[4] = {};

  int sA[16], sB[16];
#pragma unroll
  for (int j = 0; j < 16; ++j) {
    int rel = 2 * j + half;
    sA[j] = epA[(rel < degA ? rel : 0) * 2];
  }
#pragma unroll
  for (int j = 0; j < 16; ++j) {
    int rel = 2 * j + half;
    sB[j] = epB[(rel < degB ? rel : 0) * 2];
  }
  unsigned int uA[16], uB[16];
#pragma unroll
  for (int j = 0; j < 16; ++j)
    uA[j] = *(const unsigned int*)(sp + (size_t)sA[j] * NCLASS);
#pragma unroll
  for (int j = 0; j < 16; ++j)
    uB[j] = *(const unsigned int*)(sp + (size_t)sB[j] * NCLASS);
#pragma unroll
  for (int j = 0; j < 16; ++j) {
    int rel = 2 * j + half;
    float w = (rel < degA) ? __int_as_float(epA[rel * 2 + 1]) : 0.0f;
    axA[j & 3] += w * __int_as_float(uA[j] << 16);
    ayA[j & 3] += w * __int_as_float(uA[j] & 0xffff0000u);
  }
#pragma unroll
  for (int j = 0; j < 16; ++j) {
    int rel = 2 * j + half;
    float w = (rel < degB) ? __int_as_float(epB[rel * 2 + 1]) : 0.0f;
    axB[j & 3] += w * __int_as_float(uB[j] << 16);
    ayB[j & 3] += w * __int_as_float(uB[j] & 0xffff0000u);
  }
  for (int it = 32; it < degA; it += 16) {
    int2 ed[8];
#pragma unroll
    for (int j = 0; j < 8; ++j) {
      int rel = it + 2 * j + half;
      ed[j] = *(const int2*)(epA + (rel < degA ? rel : 0) * 2);
    }
    unsigned int uu[8];
#pragma unroll
    for (int j = 0; j < 8; ++j)
      uu[j] = *(const unsigned int*)(sp + (size_t)ed[j].x * NCLASS);
#pragma unroll
    for (int j = 0; j < 8; ++j) {
      int rel = it + 2 * j + half;
      float w = (rel < degA) ? __int_as_float(ed[j].y) : 0.0f;
      axA[j & 3] += w * __int_as_float(uu[j] << 16);
      ayA[j & 3] += w * __int_as_float(uu[j] & 0xffff0000u);
    }
  }
  for (int it = 32; it < degB; it += 16) {
    int2 ed[8];
#pragma unroll
    for (int j = 0; j < 8; ++j) {
      int rel = it + 2 * j + half;
      ed[j] = *(const int2*)(epB + (rel < degB ? rel : 0) * 2);
    }
    unsigned int uu[8];
#pragma unroll
    for (int j = 0; j < 8; ++j)
      uu[j] = *(const unsigned int*)(sp + (size_t)ed[j].x * NCLASS);
#pragma unroll
    for (int j = 0; j < 8; ++j) {
      int rel = it + 2 * j + half;
      float w = (rel < degB) ? __int_as_float(ed[j].y) : 0.0f;
      axB[j & 3] += w * __int_as_float(uu[j] << 16);
      ayB[j & 3] += w * __int_as_float(uu[j] & 0xffff0000u);
    }
  }

  float sxA = ((axA[0] + axA[1]) + (axA[2] + axA[3]));
  float syA = ((ayA[0] + ayA[1]) + (ayA[2] + ayA[3]));
  float sxB = ((axB[0] + axB[1]) + (axB[2] + axB[3]));
  float syB = ((ayB[0] + ayB[1]) + (ayB[2] + ayB[3]));
  sxA += __shfl_xor(sxA, 32, 64);
  syA += __shfl_xor(syA, 32, 64);
  sxB += __shfl_xor(sxB, 32, 64);
  syB += __shfl_xor(syB, 32, 64);

  bool valid = (hl < 20);
  float2 bv = *(const float2*)&bias[col];
  float vxA = sxA + bv.x, vyA = syA + bv.y;
  float vxB = sxB + bv.x, vyB = syB + bv.y;

  float mA = valid ? fmaxf(vxA, vyA) : -INFINITY;
  float mB = valid ? fmaxf(vxB, vyB) : -INFINITY;
#pragma unroll
  for (int d = 32; d; d >>= 1) {
    mA = fmaxf(mA, __shfl_xor(mA, d, 64));
    mB = fmaxf(mB, __shfl_xor(mB, d, 64));
  }
  float exA = (valid && half == 0) ? (expf(vxA - mA) + expf(vyA - mA)) : 0.0f;
  float exB = (valid && half == 0) ? (expf(vxB - mB) + expf(vyB - mB)) : 0.0f;
  float sA2 = exA, sB2 = exB;
#pragma unroll
  for (int d = 32; d; d >>= 1) {
    sA2 += __shfl_xor(sA2, d, 64);
    sB2 += __shfl_xor(sB2, d, 64);
  }
  if (valid) {
    if (half == 0) {
      float ls = logf(sA2);
      *(float2*)&out[(size_t)nA * NCLASS + hl * 2] =
          make_float2(vxA - mA - ls, vyA - mA - ls);
    } else {
      float ls = logf(sB2);
      *(float2*)&out[(size_t)nB * NCLASS + hl * 2] =
          make_float2(vxB - mB - ls, vyB - mB - ls);
    }
  }
}

extern "C" void kernel_launch(void* const* d_in, const int* in_sizes, int n_in,
                              void* d_out, int out_size, void* d_ws, size_t ws_size,
                              hipStream_t stream) {
  const float* x   = (const float*)d_in[0];
  const int*   src = (const int*)d_in[1];
  const int*   dst = (const int*)d_in[2];
  const float* ew  = (const float*)d_in[3];
  const float* W[7]; const float* b[7];
  for (int i = 0; i < 7; ++i) {
    W[i] = (const float*)d_in[4 + 2 * i];
    b[i] = (const float*)d_in[5 + 2 * i];
  }
  int N = in_sizes[0] / NFEAT;   // 65536
  int E = in_sizes[1];           // 1048576

  char* ws = (char*)d_ws;
  int*      off     = (int*)(ws + 0);                 // (N+1) ints
  int*      bsum    = (int*)(ws + (1ll << 20));       // 256 ints
  int*      cnt4    = (int*)(ws + (2ll << 20));       // 4N ints = 1MB [2,3)
  int4*     sb4     = (int4*)(ws + (3ll << 20));      // N int4 = 1MB  [3,4)
  int2*     edata   = (int2*)(ws + (4ll << 20));      // E int2 = 8MB  [4,12)
  int*      rank    = (int*)(ws + (12ll << 20));      // E ints = 4MB  [12,16)
  ushort_t* SA      = (ushort_t*)(ws + (16ll << 20)); // N*64 bf16 = 8MB [16,24)
  ushort_t* SB      = (ushort_t*)(ws + (24ll << 20)); // N*64 bf16 = 8MB [24,32)
  float*    hA      = (float*)(ws + (32ll << 20));    // 16MB (h2 / h4)
  float*    hB      = (float*)(ws + (48ll << 20));    // 16MB (h3)

  // ---- build dst-CSR ----
  (void)hipMemsetAsync(cnt4, 0, (size_t)4 * N * sizeof(int), stream);
  rank_k<<<(E / 4 + 255) / 256, 256, 0, stream>>>(dst, cnt4, rank, E, N);
  int nb = (N + 255) / 256;
  scan1_k<<<nb, 256, 0, stream>>>(cnt4, off, bsum, sb4, N);
  scan2_k<<<1, 256, 0, stream>>>(bsum, nb);
  scan3_k<<<nb, 256, 0, stream>>>(off, bsum, N, E);
  fill_k<<<(E / 4 + 255) / 256, 256, 0, stream>>>(src, dst, ew, off, rank,
                                                  (const int*)sb4, edata, E);

  int gb_gemm = N / 64;
  int gb_agg  = N / 8;   // 2 nodes/wave, 4 waves/block

  // L1 GEMM: S1 = x @ W1
  gemm_k<128, 64><<<gb_gemm, 256, 0, stream>>>(x, W[0], SA, N);
  // K2: h1 = relu(agg(S1)+b1); S2 = h1@W2
  aggemm_k<64, false><<<gb_agg, 256, 0, stream>>>(SA, edata, off, b[0], nullptr,
                                                  W[1], SB, nullptr, N);
  // K3: h2 = relu(agg(S2)+b2); S3 = h2@W3; keep h2
  aggemm_k<64, true><<<gb_agg, 256, 0, stream>>>(SB, edata, off, b[1], nullptr,
                                                 W[2], SA, hA, N);
  // K4: h3 = relu(agg(S3)+b3)+h2; S4 = h3@W4; keep h3
  aggemm_k<64, true><<<gb_agg, 256, 0, stream>>>(SA, edata, off, b[2], hA,
                                                 W[3], SB, hB, N);
  // K5: h4 = relu(agg(S4)+b4)+h3; S5 = h4@W5; keep h4 (h2 dead -> reuse hA)
  aggemm_k<64, true><<<gb_agg, 256, 0, stream>>>(SB, edata, off, b[3], hB,
                                                 W[4], SA, hA, N);
  // K6: h5 = relu(agg(S5)+b5)+h4; S6 = h5@W6
  aggemm_k<64, false><<<gb_agg, 256, 0, stream>>>(SA, edata, off, b[4], hA,
                                                  W[5], SB, nullptr, N);
  // K7: h6 = relu(agg(S6)+b6); S7 = h6@W7 (64->40)
  aggemm_k<40, false><<<gb_agg, 256, 0, stream>>>(SB, edata, off, b[5], nullptr,
                                                  W[6], SA, nullptr, N);
  // K8: out = log_softmax(agg(S7)+b7)
  agg_final_k<<<gb_agg, 256, 0, stream>>>(SA, edata, off, b[6], (float*)d_out, N);
}